// Round 17
// baseline (176.422 us; speedup 1.0000x reference)
//
#include <hip/hip_runtime.h>
#include <hip/hip_bf16.h>

// Problem constants: B=4, N=4096, C=768, H=W=128, N0=H*W=16384
#define BB 4
#define NN 4096
#define CC 768
#define HH 128
#define WW 128
#define N0 (HH * WW)
#define HW (HH * WW)
#define EPS 1e-6f
#define NSAMP (BB * N0)          // 65536
#define NPIX  (BB * HW)          // 65536
#define NTOK  (BB * NN)          // 16384

// conv tiling: 8x8 pixel tile x 128-channel slice, bf16 LDS halo tile
// (R6: f32 tile kills occupancy. R9: fused CSR gather serializes. R10/R14:
//  conv is VALU-issue-bound. R15: pk_fma. R16: 16B staging lanes.)
#define TP 8
#define CSUB 128
#define TROWU 136                // ushorts per cell (272B, 16B-aligned for b128)
#define NTILE (HH / TP)          // 16
#define CONV_BLOCKS (BB * (CC / CSUB) * NTILE * NTILE)   // 6144

#define XPB 16                   // pixels per k_xmap block (16 indep chains)
#define TPB 16                   // tokens per k_token block (16 indep chains)

typedef __attribute__((ext_vector_type(2))) float f32x2;

// ---------------------------------------------------------------------------
__device__ inline float bf2f(ushort u) {
    unsigned v = ((unsigned)u) << 16;
    return __uint_as_float(v);
}
__device__ inline ushort f2bf(float f) {
    __hip_bfloat16 h = __float2bfloat16(f);   // RNE
    return *reinterpret_cast<ushort*>(&h);
}
__device__ inline float4 us4_to_f4(ushort4 u) {
    float4 r;
    r.x = bf2f(u.x); r.y = bf2f(u.y); r.z = bf2f(u.z); r.w = bf2f(u.w);
    return r;
}
// unpack one u32 (2 packed bf16) into a f32x2 {lo, hi}: 2 VALU ops
__device__ inline f32x2 u32_to_f2(unsigned u) {
    f32x2 r;
    r.x = __uint_as_float(u << 16);
    r.y = __uint_as_float(u & 0xffff0000u);
    return r;
}

// ---------------------------------------------------------------------------
// K0a: pixel index per sample + integer counts per pixel segment and token segment
__global__ void k_idx(const float* __restrict__ loc,
                      const int* __restrict__ idx_agg,
                      int* __restrict__ idx_hw,
                      int* __restrict__ count_pix,
                      int* __restrict__ count_tok) {
    int i = blockIdx.x * blockDim.x + threadIdx.x;
    if (i >= NSAMP) return;
    float lx = loc[2 * i + 0];
    float ly = loc[2 * i + 1];
    float fx = 0.5f * (lx + 1.0f) * (float)WW - 0.5f;
    float fy = 0.5f * (ly + 1.0f) * (float)HH - 0.5f;
    int px = (int)rintf(fx);                 // round-half-even == jnp.round
    int py = (int)rintf(fy);
    px = min(max(px, 0), WW - 1);
    py = min(max(py, 0), HH - 1);
    int pix = py * WW + px;
    idx_hw[i] = pix;
    int b = i >> 14;                         // N0 = 16384
    atomicAdd(&count_pix[(b << 14) + pix], 1);
    atomicAdd(&count_tok[(b << 12) + idx_agg[i]], 1);
}

// ---------------------------------------------------------------------------
// K0b: 8 independent segment scans (4 pix batches, 4 tok batches); each batch
// segment sums to exactly N0 so segment bases are statically b*N0.
__global__ __launch_bounds__(1024) void k_scan(const int* __restrict__ cnt_pix,
                                               int* __restrict__ off_pix,
                                               const int* __restrict__ cnt_tok,
                                               int* __restrict__ off_tok) {
    __shared__ int wpart[16];
    __shared__ int run_sh;
    int bid = blockIdx.x;                    // 0..3 pix, 4..7 tok
    const int* cnt;
    int* off;
    int n, base, vbase;
    if (bid < 4) {
        cnt = cnt_pix; off = off_pix; n = HW;
        base = bid << 14; vbase = bid << 14;
    } else {
        cnt = cnt_tok; off = off_tok; n = NN;
        base = (bid - 4) << 12; vbase = (bid - 4) << 14;
    }
    int t = threadIdx.x;
    int lane = t & 63;
    int wid = t >> 6;                        // 0..15
    if (t == 0) run_sh = 0;
    __syncthreads();
    for (int it = 0; it < n; it += 1024) {
        int idx = it + t;
        int v = (idx < n) ? cnt[base + idx] : 0;
        int s = v;                           // inclusive wave scan
#pragma unroll
        for (int d = 1; d < 64; d <<= 1) {
            int u = __shfl_up(s, d, 64);
            if (lane >= d) s += u;
        }
        if (lane == 63) wpart[wid] = s;
        __syncthreads();
        if (wid == 0) {                      // scan the 16 wave partials
            int p = (lane < 16) ? wpart[lane] : 0;
#pragma unroll
            for (int d = 1; d < 16; d <<= 1) {
                int u = __shfl_up(p, d, 64);
                if (lane >= d) p += u;
            }
            if (lane < 16) wpart[lane] = p;
        }
        __syncthreads();
        int wbase = (wid == 0) ? 0 : wpart[wid - 1];
        int run = run_sh;
        if (idx < n) off[base + idx] = vbase + run + wbase + s - v;  // exclusive
        __syncthreads();                     // all read run_sh before update
        if (t == 0) run_sh = run + wpart[15];
        __syncthreads();
    }
}

// ---------------------------------------------------------------------------
// K0c: fill CSR sample lists (pixel-ordered and token-ordered)
__global__ void k_fill(const int* __restrict__ idx_hw,
                       const int* __restrict__ idx_agg,
                       const int* __restrict__ off_pix, int* __restrict__ fill_pix,
                       int* __restrict__ list_pix,
                       const int* __restrict__ off_tok, int* __restrict__ fill_tok,
                       int* __restrict__ list_tok) {
    int i = blockIdx.x * blockDim.x + threadIdx.x;
    if (i >= NSAMP) return;
    int b = i >> 14;
    int sp = (b << 14) + idx_hw[i];
    int p = atomicAdd(&fill_pix[sp], 1);
    list_pix[off_pix[sp] + p] = i;
    int st = (b << 12) + idx_agg[i];
    int q = atomicAdd(&fill_tok[st], 1);
    list_tok[off_tok[st] + q] = i;
}

// ---------------------------------------------------------------------------
// K1: build normalized pixel map via gather, bf16 output.
//     16 pixels per block -> 16 independent dependent-load chains (16x MLP);
//     SKIP stores for empty pixels (conv zero-fills those cells from counts).
__global__ __launch_bounds__(192) void k_xmap(const float* __restrict__ x,
                                              const int* __restrict__ idx_agg,
                                              const int* __restrict__ count_pix,
                                              const int* __restrict__ off_pix,
                                              const int* __restrict__ list_pix,
                                              ushort* __restrict__ xm) {
    int bi0 = blockIdx.x * XPB;              // 16 consecutive pixels, same batch
    int b = bi0 >> 14;
    int c4 = threadIdx.x;                    // 0..191
    const float* xb = x + (size_t)(b * NN) * CC;

    int kk[XPB], st[XPB];
#pragma unroll
    for (int p = 0; p < XPB; ++p) {
        kk[p] = count_pix[bi0 + p];
        st[p] = off_pix[bi0 + p];
    }
    float4 acc[XPB];
#pragma unroll
    for (int p = 0; p < XPB; ++p) acc[p] = make_float4(0.f, 0.f, 0.f, 0.f);

    int kmax = 0;
#pragma unroll
    for (int p = 0; p < XPB; ++p) kmax = max(kmax, kk[p]);

    for (int j = 0; j < kmax; ++j) {
#pragma unroll
        for (int p = 0; p < XPB; ++p) {
            if (j < kk[p]) {
                int i = list_pix[st[p] + j];
                int tok = idx_agg[i];
                float4 v = ((const float4*)(xb + (size_t)tok * CC))[c4];
                acc[p].x += v.x; acc[p].y += v.y;
                acc[p].z += v.z; acc[p].w += v.w;
            }
        }
    }
#pragma unroll
    for (int p = 0; p < XPB; ++p) {
        if (kk[p] > 0) {                     // empty rows never read downstream
            float inv = 1.0f / ((float)kk[p] + EPS);
            ushort4 o;
            o.x = f2bf(acc[p].x * inv); o.y = f2bf(acc[p].y * inv);
            o.z = f2bf(acc[p].z * inv); o.w = f2bf(acc[p].w * inv);
            ((ushort4*)(xm + (size_t)(bi0 + p) * CC))[c4] = o;
        }
    }
}

// ---------------------------------------------------------------------------
// K2: depthwise 3x3 conv + bias, LDS-tiled (8x8 pixels x 128 ch per block).
//     bf16 halo tile; count==0 cells zero-filled without global read.
//     f32x2 packed accumulation (v_pk_fma_f32) + 16B staging lanes.
__global__ __launch_bounds__(256, 5) void k_conv(const ushort* __restrict__ xm,
                                                 const int* __restrict__ count_pix,
                                                 const float* __restrict__ w_dw,
                                                 const float* __restrict__ b_dw,
                                                 ushort* __restrict__ ym) {
    __shared__ ushort tile[(TP + 2) * (TP + 2) * TROWU];   // 10*10*136*2 = 27.2 KB
    __shared__ int cnt_halo[(TP + 2) * (TP + 2)];          // 100 ints

    int f = blockIdx.x;
    f = (f & 7) * (CONV_BLOCKS / 8) + (f >> 3);            // bijective XCD swizzle
    int tx = f & 15;
    int ty = (f >> 4) & 15;
    int cblk = (f >> 8) % 6;
    int b = f / 1536;
    int tid = threadIdx.x;

    int c0g = cblk * CSUB;                                 // global channel base
    const ushort* src = xm + (size_t)(b << 14) * CC + c0g;

    // ---- stage halo counts (100 ints; 0 outside image) ----
    if (tid < (TP + 2) * (TP + 2)) {
        int r = tid / 10;
        int c = tid - r * 10;
        int gy = ty * TP + r - 1;
        int gx = tx * TP + c - 1;
        int cnt = 0;
        if (gy >= 0 && gy < HH && gx >= 0 && gx < WW)
            cnt = count_pix[(b << 14) + gy * WW + gx];
        cnt_halo[tid] = cnt;
    }
    __syncthreads();

    // ---- stage 10x10 bf16 halo tile, 16 lanes x 16B per cell ----
    for (int idx = tid; idx < (TP + 2) * (TP + 2) * 16; idx += 256) {
        int lc = idx & 15;                                 // uint4 within cell
        int cell = idx >> 4;                               // 0..99
        int r = cell / 10;
        int c = cell - r * 10;
        uint4 v = make_uint4(0u, 0u, 0u, 0u);
        if (cnt_halo[cell] > 0) {                          // implies in-image
            int gy = ty * TP + r - 1;
            int gx = tx * TP + c - 1;
            v = ((const uint4*)(src + (size_t)(gy * WW + gx) * CC))[lc];
        }
        ((uint4*)(tile + (size_t)cell * TROWU))[lc] = v;
    }
    __syncthreads();

    // ---- per-thread: 4 channels (c4), one pixel column (px), walk 8 rows ----
    int c4 = tid & 31;
    int px = tid >> 5;                                     // 0..7

    // weights as packed pairs: wp01[t]={w[c0][t],w[c1][t]}, wp23 likewise
    f32x2 wp01[9], wp23[9];
    {
        float wreg[36];                                    // [4ch][9taps] contiguous
        const float4* wp = (const float4*)(w_dw + (size_t)(c0g + c4 * 4) * 9);
#pragma unroll
        for (int j = 0; j < 9; ++j) ((float4*)wreg)[j] = wp[j];
#pragma unroll
        for (int t = 0; t < 9; ++t) {
            wp01[t].x = wreg[0 * 9 + t]; wp01[t].y = wreg[1 * 9 + t];
            wp23[t].x = wreg[2 * 9 + t]; wp23[t].y = wreg[3 * 9 + t];
        }
    }
    float4 bias = ((const float4*)(b_dw + c0g))[c4];
    f32x2 bias01; bias01.x = bias.x; bias01.y = bias.y;
    f32x2 bias23; bias23.x = bias.z; bias23.y = bias.w;

    // sliding window as packed pairs; cell read = uint2 (4 bf16)
    f32x2 a01[3][3], a23[3][3];
#pragma unroll
    for (int i = 0; i < 2; ++i)
#pragma unroll
        for (int j = 0; j < 3; ++j) {
            uint2 u = ((const uint2*)(tile + (size_t)(i * (TP + 2) + px + j) * TROWU))[c4];
            a01[i][j] = u32_to_f2(u.x);
            a23[i][j] = u32_to_f2(u.y);
        }

    ushort* dst_base = ym + (size_t)((b << 14) + (ty * TP) * WW + tx * TP + px) * CC
                       + c0g;

#pragma unroll
    for (int oy = 0; oy < TP; ++oy) {
#pragma unroll
        for (int j = 0; j < 3; ++j) {
            uint2 u = ((const uint2*)(tile + (size_t)((oy + 2) * (TP + 2) + px + j) * TROWU))[c4];
            a01[2][j] = u32_to_f2(u.x);
            a23[2][j] = u32_to_f2(u.y);
        }

        if (cnt_halo[(oy + 1) * (TP + 2) + px + 1] > 0) {  // skip dead outputs
            f32x2 acc01 = bias01;
            f32x2 acc23 = bias23;
#pragma unroll
            for (int i = 0; i < 3; ++i) {
#pragma unroll
                for (int j = 0; j < 3; ++j) {
                    int t = i * 3 + j;
                    acc01 += a01[i][j] * wp01[t];          // v_pk_fma_f32
                    acc23 += a23[i][j] * wp23[t];
                }
            }
            ushort4 o;
            o.x = f2bf(acc01.x); o.y = f2bf(acc01.y);
            o.z = f2bf(acc23.x); o.w = f2bf(acc23.y);
            ((ushort4*)(dst_base + (size_t)oy * WW * CC))[c4] = o;
        }

#pragma unroll
        for (int j = 0; j < 3; ++j) {
            a01[0][j] = a01[1][j]; a01[1][j] = a01[2][j];
            a23[0][j] = a23[1][j]; a23[1][j] = a23[2][j];
        }
    }
}

// ---------------------------------------------------------------------------
// K3: per-token gather of conv rows, weighted avg, fused skip.
//     16 tokens per block -> 16 independent gather chains (16x MLP).
__global__ __launch_bounds__(192) void k_token(const ushort* __restrict__ ym,
                                               const float* __restrict__ x,
                                               const float* __restrict__ agg_w,
                                               const int* __restrict__ idx_hw,
                                               const int* __restrict__ count_tok,
                                               const int* __restrict__ off_tok,
                                               const int* __restrict__ list_tok,
                                               const float* __restrict__ w_skip,
                                               float* __restrict__ out) {
    int bi0 = blockIdx.x * TPB;              // 16 consecutive tokens, same batch
    int b = bi0 >> 12;                       // NN = 4096
    int c4 = threadIdx.x;
    const ushort* yb = ym + (size_t)(b << 14) * CC;

    int kk[TPB], st[TPB];
#pragma unroll
    for (int p = 0; p < TPB; ++p) {
        kk[p] = count_tok[bi0 + p];
        st[p] = off_tok[bi0 + p];
    }
    float4 acc[TPB];
    float tw[TPB];
#pragma unroll
    for (int p = 0; p < TPB; ++p) {
        acc[p] = make_float4(0.f, 0.f, 0.f, 0.f);
        tw[p] = 0.f;
    }

    int kmax = 0;
#pragma unroll
    for (int p = 0; p < TPB; ++p) kmax = max(kmax, kk[p]);

    for (int j = 0; j < kmax; ++j) {
#pragma unroll
        for (int p = 0; p < TPB; ++p) {
            if (j < kk[p]) {
                int i = list_tok[st[p] + j];
                float w = agg_w[i];
                int pix = idx_hw[i];
                float4 v = us4_to_f4(((const ushort4*)(yb + (size_t)pix * CC))[c4]);
                acc[p].x += w * v.x; acc[p].y += w * v.y;
                acc[p].z += w * v.z; acc[p].w += w * v.w;
                tw[p] += w;
            }
        }
    }

    float4 ws = ((const float4*)w_skip)[c4];
#pragma unroll
    for (int p = 0; p < TPB; ++p) {
        float inv = 1.0f / (tw[p] + EPS);
        float4 xv = ((const float4*)(x + (size_t)(bi0 + p) * CC))[c4];
        float4 o;
        o.x = acc[p].x * inv + xv.x * ws.x;
        o.y = acc[p].y * inv + xv.y * ws.y;
        o.z = acc[p].z * inv + xv.z * ws.z;
        o.w = acc[p].w * inv + xv.w * ws.w;
        ((float4*)(out + (size_t)(bi0 + p) * CC))[c4] = o;
    }
}

// ---------------------------------------------------------------------------
extern "C" void kernel_launch(void* const* d_in, const int* in_sizes, int n_in,
                              void* d_out, int out_size, void* d_ws, size_t ws_size,
                              hipStream_t stream) {
    const float* x       = (const float*)d_in[0];   // [B,N,C]
    const float* loc     = (const float*)d_in[1];   // [B,N0,2]
    const int*   idx_agg = (const int*)d_in[2];     // [B,N0]
    const float* agg_w   = (const float*)d_in[3];   // [B,N0]
    const float* w_dw    = (const float*)d_in[6];   // [C,1,3,3]
    const float* b_dw    = (const float*)d_in[7];   // [C]
    const float* w_skip  = (const float*)d_in[8];   // [C]
    float* out = (float*)d_out;
    char* ws = (char*)d_ws;

    size_t off = 0;
    // zeroed region (one small memset): counts + fill cursors
    int* count_pix = (int*)(ws + off); off += (size_t)NPIX * 4;
    int* fill_pix  = (int*)(ws + off); off += (size_t)NPIX * 4;
    int* count_tok = (int*)(ws + off); off += (size_t)NTOK * 4;
    int* fill_tok  = (int*)(ws + off); off += (size_t)NTOK * 4;
    size_t zero_bytes = off;
    // fully-written regions
    int* idx_hw   = (int*)(ws + off); off += (size_t)NSAMP * 4;
    int* off_pix  = (int*)(ws + off); off += (size_t)NPIX * 4;
    int* list_pix = (int*)(ws + off); off += (size_t)NSAMP * 4;
    int* off_tok  = (int*)(ws + off); off += (size_t)NTOK * 4;
    int* list_tok = (int*)(ws + off); off += (size_t)NSAMP * 4;
    ushort* xm = (ushort*)(ws + off); off += (size_t)NPIX * CC * 2;   // 100.7 MB bf16
    ushort* ym = (ushort*)(ws + off); off += (size_t)NPIX * CC * 2;   // 100.7 MB bf16
    // total ~202.7 MB — within the proven-safe workspace budget (R0 used 252 MB)

    hipMemsetAsync(ws, 0, zero_bytes, stream);

    hipLaunchKernelGGL(k_idx, dim3(NSAMP / 256), dim3(256), 0, stream,
                       loc, idx_agg, idx_hw, count_pix, count_tok);
    hipLaunchKernelGGL(k_scan, dim3(8), dim3(1024), 0, stream,
                       count_pix, off_pix, count_tok, off_tok);
    hipLaunchKernelGGL(k_fill, dim3(NSAMP / 256), dim3(256), 0, stream,
                       idx_hw, idx_agg, off_pix, fill_pix, list_pix,
                       off_tok, fill_tok, list_tok);
    hipLaunchKernelGGL(k_xmap, dim3(NPIX / XPB), dim3(192), 0, stream,
                       x, idx_agg, count_pix, off_pix, list_pix, xm);
    hipLaunchKernelGGL(k_conv, dim3(CONV_BLOCKS), dim3(256), 0, stream,
                       xm, count_pix, w_dw, b_dw, ym);
    hipLaunchKernelGGL(k_token, dim3(NTOK / TPB), dim3(192), 0, stream,
                       ym, x, agg_w, idx_hw, count_tok, off_tok, list_tok,
                       w_skip, out);
}

// Round 18
// 145.162 us; speedup vs baseline: 1.2153x; 1.2153x over previous
//
#include <hip/hip_runtime.h>
#include <hip/hip_bf16.h>

// Problem constants: B=4, N=4096, C=768, H=W=128, N0=H*W=16384
#define BB 4
#define NN 4096
#define CC 768
#define HH 128
#define WW 128
#define N0 (HH * WW)
#define HW (HH * WW)
#define EPS 1e-6f
#define NSAMP (BB * N0)          // 65536
#define NPIX  (BB * HW)          // 65536
#define NTOK  (BB * NN)          // 16384

// conv tiling: 8x8 pixel tile x 128-channel slice, bf16 LDS halo tile
// (R6: f32 tile kills occupancy. R9: fused CSR gather serializes. R10/R14:
//  conv is VALU-issue-bound. R15: pk_fma. R16: 16B staging lanes.
//  R17: 16-chain MLP kills occupancy — 8 is the sweet spot.)
#define TP 8
#define CSUB 128
#define TROWU 136                // ushorts per cell (272B, 16B-aligned for b128)
#define NTILE (HH / TP)          // 16
#define CONV_BLOCKS (BB * (CC / CSUB) * NTILE * NTILE)   // 6144

#define XPB 8                    // pixels per k_xmap block (8 indep chains)
#define TPB 8                    // tokens per k_token block (8 indep chains)

typedef __attribute__((ext_vector_type(2))) float f32x2;

// ---------------------------------------------------------------------------
__device__ inline float bf2f(ushort u) {
    unsigned v = ((unsigned)u) << 16;
    return __uint_as_float(v);
}
__device__ inline ushort f2bf(float f) {
    __hip_bfloat16 h = __float2bfloat16(f);   // RNE
    return *reinterpret_cast<ushort*>(&h);
}
__device__ inline float4 us4_to_f4(ushort4 u) {
    float4 r;
    r.x = bf2f(u.x); r.y = bf2f(u.y); r.z = bf2f(u.z); r.w = bf2f(u.w);
    return r;
}
// unpack one u32 (2 packed bf16) into a f32x2 {lo, hi}: 2 VALU ops
__device__ inline f32x2 u32_to_f2(unsigned u) {
    f32x2 r;
    r.x = __uint_as_float(u << 16);
    r.y = __uint_as_float(u & 0xffff0000u);
    return r;
}

// ---------------------------------------------------------------------------
// K0a: pixel index per sample + integer counts per pixel segment and token segment
__global__ void k_idx(const float* __restrict__ loc,
                      const int* __restrict__ idx_agg,
                      int* __restrict__ idx_hw,
                      int* __restrict__ count_pix,
                      int* __restrict__ count_tok) {
    int i = blockIdx.x * blockDim.x + threadIdx.x;
    if (i >= NSAMP) return;
    float lx = loc[2 * i + 0];
    float ly = loc[2 * i + 1];
    float fx = 0.5f * (lx + 1.0f) * (float)WW - 0.5f;
    float fy = 0.5f * (ly + 1.0f) * (float)HH - 0.5f;
    int px = (int)rintf(fx);                 // round-half-even == jnp.round
    int py = (int)rintf(fy);
    px = min(max(px, 0), WW - 1);
    py = min(max(py, 0), HH - 1);
    int pix = py * WW + px;
    idx_hw[i] = pix;
    int b = i >> 14;                         // N0 = 16384
    atomicAdd(&count_pix[(b << 14) + pix], 1);
    atomicAdd(&count_tok[(b << 12) + idx_agg[i]], 1);
}

// ---------------------------------------------------------------------------
// K0b: 8 independent segment scans, SINGLE-PASS (R18): each thread owns
// CHUNK consecutive counts in registers (compile-time CHUNK -> no scratch),
// serial-sums, one wave+block scan round, writes its chunk's offsets.
// Replaces 16 syncthreads-heavy tile rounds with 1.
template <int CHUNK>
__device__ inline void scan_seg(const int* __restrict__ cnt, int* __restrict__ off,
                                int base, int vbase, int* wpart) {
    int t = threadIdx.x;
    int lane = t & 63;
    int wid = t >> 6;                        // 0..15
    int lo = t * CHUNK;

    int vals[CHUNK];
    int s = 0;
#pragma unroll
    for (int k = 0; k < CHUNK; ++k) {
        vals[k] = cnt[base + lo + k];
        s += vals[k];
    }
    int ws = s;                              // inclusive wave scan of chunk sums
#pragma unroll
    for (int d = 1; d < 64; d <<= 1) {
        int u = __shfl_up(ws, d, 64);
        if (lane >= d) ws += u;
    }
    if (lane == 63) wpart[wid] = ws;
    __syncthreads();
    if (wid == 0) {                          // scan the 16 wave partials
        int p = (lane < 16) ? wpart[lane] : 0;
#pragma unroll
        for (int d = 1; d < 16; d <<= 1) {
            int u = __shfl_up(p, d, 64);
            if (lane >= d) p += u;
        }
        if (lane < 16) wpart[lane] = p;
    }
    __syncthreads();
    int run = vbase + (wid == 0 ? 0 : wpart[wid - 1]) + (ws - s);
#pragma unroll
    for (int k = 0; k < CHUNK; ++k) {
        off[base + lo + k] = run;
        run += vals[k];
    }
}

__global__ __launch_bounds__(1024) void k_scan(const int* __restrict__ cnt_pix,
                                               int* __restrict__ off_pix,
                                               const int* __restrict__ cnt_tok,
                                               int* __restrict__ off_tok) {
    __shared__ int wpart[16];
    int bid = blockIdx.x;                    // 0..3 pix, 4..7 tok
    if (bid < 4) {
        scan_seg<HW / 1024>(cnt_pix, off_pix, bid << 14, bid << 14, wpart);   // 16
    } else {
        int b = bid - 4;
        scan_seg<NN / 1024>(cnt_tok, off_tok, b << 12, b << 14, wpart);       // 4
    }
}

// ---------------------------------------------------------------------------
// K0c: fill CSR sample lists (pixel-ordered and token-ordered)
__global__ void k_fill(const int* __restrict__ idx_hw,
                       const int* __restrict__ idx_agg,
                       const int* __restrict__ off_pix, int* __restrict__ fill_pix,
                       int* __restrict__ list_pix,
                       const int* __restrict__ off_tok, int* __restrict__ fill_tok,
                       int* __restrict__ list_tok) {
    int i = blockIdx.x * blockDim.x + threadIdx.x;
    if (i >= NSAMP) return;
    int b = i >> 14;
    int sp = (b << 14) + idx_hw[i];
    int p = atomicAdd(&fill_pix[sp], 1);
    list_pix[off_pix[sp] + p] = i;
    int st = (b << 12) + idx_agg[i];
    int q = atomicAdd(&fill_tok[st], 1);
    list_tok[off_tok[st] + q] = i;
}

// ---------------------------------------------------------------------------
// K1: build normalized pixel map via gather, bf16 output.
//     8 pixels per block -> 8 independent dependent-load chains (8x MLP);
//     SKIP stores for empty pixels (conv zero-fills those cells from counts).
__global__ __launch_bounds__(192) void k_xmap(const float* __restrict__ x,
                                              const int* __restrict__ idx_agg,
                                              const int* __restrict__ count_pix,
                                              const int* __restrict__ off_pix,
                                              const int* __restrict__ list_pix,
                                              ushort* __restrict__ xm) {
    int bi0 = blockIdx.x * XPB;              // 8 consecutive pixels, same batch
    int b = bi0 >> 14;
    int c4 = threadIdx.x;                    // 0..191
    const float* xb = x + (size_t)(b * NN) * CC;

    int kk[XPB], st[XPB];
#pragma unroll
    for (int p = 0; p < XPB; ++p) {
        kk[p] = count_pix[bi0 + p];
        st[p] = off_pix[bi0 + p];
    }
    float4 acc[XPB];
#pragma unroll
    for (int p = 0; p < XPB; ++p) acc[p] = make_float4(0.f, 0.f, 0.f, 0.f);

    int kmax = 0;
#pragma unroll
    for (int p = 0; p < XPB; ++p) kmax = max(kmax, kk[p]);

    for (int j = 0; j < kmax; ++j) {
#pragma unroll
        for (int p = 0; p < XPB; ++p) {
            if (j < kk[p]) {
                int i = list_pix[st[p] + j];
                int tok = idx_agg[i];
                float4 v = ((const float4*)(xb + (size_t)tok * CC))[c4];
                acc[p].x += v.x; acc[p].y += v.y;
                acc[p].z += v.z; acc[p].w += v.w;
            }
        }
    }
#pragma unroll
    for (int p = 0; p < XPB; ++p) {
        if (kk[p] > 0) {                     // empty rows never read downstream
            float inv = 1.0f / ((float)kk[p] + EPS);
            ushort4 o;
            o.x = f2bf(acc[p].x * inv); o.y = f2bf(acc[p].y * inv);
            o.z = f2bf(acc[p].z * inv); o.w = f2bf(acc[p].w * inv);
            ((ushort4*)(xm + (size_t)(bi0 + p) * CC))[c4] = o;
        }
    }
}

// ---------------------------------------------------------------------------
// K2: depthwise 3x3 conv + bias, LDS-tiled (8x8 pixels x 128 ch per block).
//     bf16 halo tile; count==0 cells zero-filled without global read.
//     f32x2 packed accumulation (v_pk_fma_f32) + 16B staging lanes.
__global__ __launch_bounds__(256, 5) void k_conv(const ushort* __restrict__ xm,
                                                 const int* __restrict__ count_pix,
                                                 const float* __restrict__ w_dw,
                                                 const float* __restrict__ b_dw,
                                                 ushort* __restrict__ ym) {
    __shared__ ushort tile[(TP + 2) * (TP + 2) * TROWU];   // 10*10*136*2 = 27.2 KB
    __shared__ int cnt_halo[(TP + 2) * (TP + 2)];          // 100 ints

    int f = blockIdx.x;
    f = (f & 7) * (CONV_BLOCKS / 8) + (f >> 3);            // bijective XCD swizzle
    int tx = f & 15;
    int ty = (f >> 4) & 15;
    int cblk = (f >> 8) % 6;
    int b = f / 1536;
    int tid = threadIdx.x;

    int c0g = cblk * CSUB;                                 // global channel base
    const ushort* src = xm + (size_t)(b << 14) * CC + c0g;

    // ---- stage halo counts (100 ints; 0 outside image) ----
    if (tid < (TP + 2) * (TP + 2)) {
        int r = tid / 10;
        int c = tid - r * 10;
        int gy = ty * TP + r - 1;
        int gx = tx * TP + c - 1;
        int cnt = 0;
        if (gy >= 0 && gy < HH && gx >= 0 && gx < WW)
            cnt = count_pix[(b << 14) + gy * WW + gx];
        cnt_halo[tid] = cnt;
    }
    __syncthreads();

    // ---- stage 10x10 bf16 halo tile, 16 lanes x 16B per cell ----
    for (int idx = tid; idx < (TP + 2) * (TP + 2) * 16; idx += 256) {
        int lc = idx & 15;                                 // uint4 within cell
        int cell = idx >> 4;                               // 0..99
        int r = cell / 10;
        int c = cell - r * 10;
        uint4 v = make_uint4(0u, 0u, 0u, 0u);
        if (cnt_halo[cell] > 0) {                          // implies in-image
            int gy = ty * TP + r - 1;
            int gx = tx * TP + c - 1;
            v = ((const uint4*)(src + (size_t)(gy * WW + gx) * CC))[lc];
        }
        ((uint4*)(tile + (size_t)cell * TROWU))[lc] = v;
    }
    __syncthreads();

    // ---- per-thread: 4 channels (c4), one pixel column (px), walk 8 rows ----
    int c4 = tid & 31;
    int px = tid >> 5;                                     // 0..7

    // weights as packed pairs: wp01[t]={w[c0][t],w[c1][t]}, wp23 likewise
    f32x2 wp01[9], wp23[9];
    {
        float wreg[36];                                    // [4ch][9taps] contiguous
        const float4* wp = (const float4*)(w_dw + (size_t)(c0g + c4 * 4) * 9);
#pragma unroll
        for (int j = 0; j < 9; ++j) ((float4*)wreg)[j] = wp[j];
#pragma unroll
        for (int t = 0; t < 9; ++t) {
            wp01[t].x = wreg[0 * 9 + t]; wp01[t].y = wreg[1 * 9 + t];
            wp23[t].x = wreg[2 * 9 + t]; wp23[t].y = wreg[3 * 9 + t];
        }
    }
    float4 bias = ((const float4*)(b_dw + c0g))[c4];
    f32x2 bias01; bias01.x = bias.x; bias01.y = bias.y;
    f32x2 bias23; bias23.x = bias.z; bias23.y = bias.w;

    // sliding window as packed pairs; cell read = uint2 (4 bf16)
    f32x2 a01[3][3], a23[3][3];
#pragma unroll
    for (int i = 0; i < 2; ++i)
#pragma unroll
        for (int j = 0; j < 3; ++j) {
            uint2 u = ((const uint2*)(tile + (size_t)(i * (TP + 2) + px + j) * TROWU))[c4];
            a01[i][j] = u32_to_f2(u.x);
            a23[i][j] = u32_to_f2(u.y);
        }

    ushort* dst_base = ym + (size_t)((b << 14) + (ty * TP) * WW + tx * TP + px) * CC
                       + c0g;

#pragma unroll
    for (int oy = 0; oy < TP; ++oy) {
#pragma unroll
        for (int j = 0; j < 3; ++j) {
            uint2 u = ((const uint2*)(tile + (size_t)((oy + 2) * (TP + 2) + px + j) * TROWU))[c4];
            a01[2][j] = u32_to_f2(u.x);
            a23[2][j] = u32_to_f2(u.y);
        }

        if (cnt_halo[(oy + 1) * (TP + 2) + px + 1] > 0) {  // skip dead outputs
            f32x2 acc01 = bias01;
            f32x2 acc23 = bias23;
#pragma unroll
            for (int i = 0; i < 3; ++i) {
#pragma unroll
                for (int j = 0; j < 3; ++j) {
                    int t = i * 3 + j;
                    acc01 += a01[i][j] * wp01[t];          // v_pk_fma_f32
                    acc23 += a23[i][j] * wp23[t];
                }
            }
            ushort4 o;
            o.x = f2bf(acc01.x); o.y = f2bf(acc01.y);
            o.z = f2bf(acc23.x); o.w = f2bf(acc23.y);
            ((ushort4*)(dst_base + (size_t)oy * WW * CC))[c4] = o;
        }

#pragma unroll
        for (int j = 0; j < 3; ++j) {
            a01[0][j] = a01[1][j]; a01[1][j] = a01[2][j];
            a23[0][j] = a23[1][j]; a23[1][j] = a23[2][j];
        }
    }
}

// ---------------------------------------------------------------------------
// K3: per-token gather of conv rows, weighted avg, fused skip.
//     8 tokens per block -> 8 independent gather chains (8x MLP).
__global__ __launch_bounds__(192) void k_token(const ushort* __restrict__ ym,
                                               const float* __restrict__ x,
                                               const float* __restrict__ agg_w,
                                               const int* __restrict__ idx_hw,
                                               const int* __restrict__ count_tok,
                                               const int* __restrict__ off_tok,
                                               const int* __restrict__ list_tok,
                                               const float* __restrict__ w_skip,
                                               float* __restrict__ out) {
    int bi0 = blockIdx.x * TPB;              // 8 consecutive tokens, same batch
    int b = bi0 >> 12;                       // NN = 4096
    int c4 = threadIdx.x;
    const ushort* yb = ym + (size_t)(b << 14) * CC;

    int kk[TPB], st[TPB];
#pragma unroll
    for (int p = 0; p < TPB; ++p) {
        kk[p] = count_tok[bi0 + p];
        st[p] = off_tok[bi0 + p];
    }
    float4 acc[TPB];
    float tw[TPB];
#pragma unroll
    for (int p = 0; p < TPB; ++p) {
        acc[p] = make_float4(0.f, 0.f, 0.f, 0.f);
        tw[p] = 0.f;
    }

    int kmax = 0;
#pragma unroll
    for (int p = 0; p < TPB; ++p) kmax = max(kmax, kk[p]);

    for (int j = 0; j < kmax; ++j) {
#pragma unroll
        for (int p = 0; p < TPB; ++p) {
            if (j < kk[p]) {
                int i = list_tok[st[p] + j];
                float w = agg_w[i];
                int pix = idx_hw[i];
                float4 v = us4_to_f4(((const ushort4*)(yb + (size_t)pix * CC))[c4]);
                acc[p].x += w * v.x; acc[p].y += w * v.y;
                acc[p].z += w * v.z; acc[p].w += w * v.w;
                tw[p] += w;
            }
        }
    }

    float4 ws = ((const float4*)w_skip)[c4];
#pragma unroll
    for (int p = 0; p < TPB; ++p) {
        float inv = 1.0f / (tw[p] + EPS);
        float4 xv = ((const float4*)(x + (size_t)(bi0 + p) * CC))[c4];
        float4 o;
        o.x = acc[p].x * inv + xv.x * ws.x;
        o.y = acc[p].y * inv + xv.y * ws.y;
        o.z = acc[p].z * inv + xv.z * ws.z;
        o.w = acc[p].w * inv + xv.w * ws.w;
        ((float4*)(out + (size_t)(bi0 + p) * CC))[c4] = o;
    }
}

// ---------------------------------------------------------------------------
extern "C" void kernel_launch(void* const* d_in, const int* in_sizes, int n_in,
                              void* d_out, int out_size, void* d_ws, size_t ws_size,
                              hipStream_t stream) {
    const float* x       = (const float*)d_in[0];   // [B,N,C]
    const float* loc     = (const float*)d_in[1];   // [B,N0,2]
    const int*   idx_agg = (const int*)d_in[2];     // [B,N0]
    const float* agg_w   = (const float*)d_in[3];   // [B,N0]
    const float* w_dw    = (const float*)d_in[6];   // [C,1,3,3]
    const float* b_dw    = (const float*)d_in[7];   // [C]
    const float* w_skip  = (const float*)d_in[8];   // [C]
    float* out = (float*)d_out;
    char* ws = (char*)d_ws;

    size_t off = 0;
    // zeroed region (one small memset): counts + fill cursors
    int* count_pix = (int*)(ws + off); off += (size_t)NPIX * 4;
    int* fill_pix  = (int*)(ws + off); off += (size_t)NPIX * 4;
    int* count_tok = (int*)(ws + off); off += (size_t)NTOK * 4;
    int* fill_tok  = (int*)(ws + off); off += (size_t)NTOK * 4;
    size_t zero_bytes = off;
    // fully-written regions
    int* idx_hw   = (int*)(ws + off); off += (size_t)NSAMP * 4;
    int* off_pix  = (int*)(ws + off); off += (size_t)NPIX * 4;
    int* list_pix = (int*)(ws + off); off += (size_t)NSAMP * 4;
    int* off_tok  = (int*)(ws + off); off += (size_t)NTOK * 4;
    int* list_tok = (int*)(ws + off); off += (size_t)NSAMP * 4;
    ushort* xm = (ushort*)(ws + off); off += (size_t)NPIX * CC * 2;   // 100.7 MB bf16
    ushort* ym = (ushort*)(ws + off); off += (size_t)NPIX * CC * 2;   // 100.7 MB bf16
    // total ~202.7 MB — within the proven-safe workspace budget (R0 used 252 MB)

    hipMemsetAsync(ws, 0, zero_bytes, stream);

    hipLaunchKernelGGL(k_idx, dim3(NSAMP / 256), dim3(256), 0, stream,
                       loc, idx_agg, idx_hw, count_pix, count_tok);
    hipLaunchKernelGGL(k_scan, dim3(8), dim3(1024), 0, stream,
                       count_pix, off_pix, count_tok, off_tok);
    hipLaunchKernelGGL(k_fill, dim3(NSAMP / 256), dim3(256), 0, stream,
                       idx_hw, idx_agg, off_pix, fill_pix, list_pix,
                       off_tok, fill_tok, list_tok);
    hipLaunchKernelGGL(k_xmap, dim3(NPIX / XPB), dim3(192), 0, stream,
                       x, idx_agg, count_pix, off_pix, list_pix, xm);
    hipLaunchKernelGGL(k_conv, dim3(CONV_BLOCKS), dim3(256), 0, stream,
                       xm, count_pix, w_dw, b_dw, ym);
    hipLaunchKernelGGL(k_token, dim3(NTOK / TPB), dim3(192), 0, stream,
                       ym, x, agg_w, idx_hw, count_tok, off_tok, list_tok,
                       w_skip, out);
}

// Round 19
// 141.472 us; speedup vs baseline: 1.2470x; 1.0261x over previous
//
#include <hip/hip_runtime.h>
#include <hip/hip_bf16.h>

// Problem constants: B=4, N=4096, C=768, H=W=128, N0=H*W=16384
#define BB 4
#define NN 4096
#define CC 768
#define HH 128
#define WW 128
#define N0 (HH * WW)
#define HW (HH * WW)
#define EPS 1e-6f
#define NSAMP (BB * N0)          // 65536
#define NPIX  (BB * HW)          // 65536
#define NTOK  (BB * NN)          // 16384

// conv tiling: 8x8 pixel tile x 128-channel slice, bf16 LDS halo tile
// (R6: f32 tile kills occupancy. R9: fused CSR gather serializes. R10/R14:
//  conv is VALU-issue-bound. R15: pk_fma. R16: 16B staging lanes.
//  R17: 16-chain MLP kills occupancy — 8 is the sweet spot. R18: 1-pass scan.)
#define TP 8
#define CSUB 128
#define TROWU 136                // ushorts per cell (272B, 16B-aligned for b128)
#define NTILE (HH / TP)          // 16
#define CONV_BLOCKS (BB * (CC / CSUB) * NTILE * NTILE)   // 6144

#define XPB 8                    // pixels per k_xmap block (8 indep chains)
#define TPB 8                    // tokens per k_token block (8 indep chains)

typedef __attribute__((ext_vector_type(2))) float f32x2;

// ---------------------------------------------------------------------------
__device__ inline float bf2f(ushort u) {
    unsigned v = ((unsigned)u) << 16;
    return __uint_as_float(v);
}
__device__ inline ushort f2bf(float f) {
    __hip_bfloat16 h = __float2bfloat16(f);   // RNE
    return *reinterpret_cast<ushort*>(&h);
}
__device__ inline float4 us4_to_f4(ushort4 u) {
    float4 r;
    r.x = bf2f(u.x); r.y = bf2f(u.y); r.z = bf2f(u.z); r.w = bf2f(u.w);
    return r;
}
// unpack one u32 (2 packed bf16) into a f32x2 {lo, hi}: 2 VALU ops
__device__ inline f32x2 u32_to_f2(unsigned u) {
    f32x2 r;
    r.x = __uint_as_float(u << 16);
    r.y = __uint_as_float(u & 0xffff0000u);
    return r;
}

// ---------------------------------------------------------------------------
// K0a: pixel index per sample + integer counts per pixel segment and token segment
__global__ void k_idx(const float* __restrict__ loc,
                      const int* __restrict__ idx_agg,
                      int* __restrict__ idx_hw,
                      int* __restrict__ count_pix,
                      int* __restrict__ count_tok) {
    int i = blockIdx.x * blockDim.x + threadIdx.x;
    if (i >= NSAMP) return;
    float lx = loc[2 * i + 0];
    float ly = loc[2 * i + 1];
    float fx = 0.5f * (lx + 1.0f) * (float)WW - 0.5f;
    float fy = 0.5f * (ly + 1.0f) * (float)HH - 0.5f;
    int px = (int)rintf(fx);                 // round-half-even == jnp.round
    int py = (int)rintf(fy);
    px = min(max(px, 0), WW - 1);
    py = min(max(py, 0), HH - 1);
    int pix = py * WW + px;
    idx_hw[i] = pix;
    int b = i >> 14;                         // N0 = 16384
    atomicAdd(&count_pix[(b << 14) + pix], 1);
    atomicAdd(&count_tok[(b << 12) + idx_agg[i]], 1);
}

// ---------------------------------------------------------------------------
// K0b: 8 independent segment scans, single-pass (R18).
template <int CHUNK>
__device__ inline void scan_seg(const int* __restrict__ cnt, int* __restrict__ off,
                                int base, int vbase, int* wpart) {
    int t = threadIdx.x;
    int lane = t & 63;
    int wid = t >> 6;                        // 0..15
    int lo = t * CHUNK;

    int vals[CHUNK];
    int s = 0;
#pragma unroll
    for (int k = 0; k < CHUNK; ++k) {
        vals[k] = cnt[base + lo + k];
        s += vals[k];
    }
    int ws = s;                              // inclusive wave scan of chunk sums
#pragma unroll
    for (int d = 1; d < 64; d <<= 1) {
        int u = __shfl_up(ws, d, 64);
        if (lane >= d) ws += u;
    }
    if (lane == 63) wpart[wid] = ws;
    __syncthreads();
    if (wid == 0) {                          // scan the 16 wave partials
        int p = (lane < 16) ? wpart[lane] : 0;
#pragma unroll
        for (int d = 1; d < 16; d <<= 1) {
            int u = __shfl_up(p, d, 64);
            if (lane >= d) p += u;
        }
        if (lane < 16) wpart[lane] = p;
    }
    __syncthreads();
    int run = vbase + (wid == 0 ? 0 : wpart[wid - 1]) + (ws - s);
#pragma unroll
    for (int k = 0; k < CHUNK; ++k) {
        off[base + lo + k] = run;
        run += vals[k];
    }
}

__global__ __launch_bounds__(1024) void k_scan(const int* __restrict__ cnt_pix,
                                               int* __restrict__ off_pix,
                                               const int* __restrict__ cnt_tok,
                                               int* __restrict__ off_tok) {
    __shared__ int wpart[16];
    int bid = blockIdx.x;                    // 0..3 pix, 4..7 tok
    if (bid < 4) {
        scan_seg<HW / 1024>(cnt_pix, off_pix, bid << 14, bid << 14, wpart);   // 16
    } else {
        int b = bid - 4;
        scan_seg<NN / 1024>(cnt_tok, off_tok, b << 12, b << 14, wpart);       // 4
    }
}

// ---------------------------------------------------------------------------
// K0c: fill CSR sample lists (pixel-ordered and token-ordered)
__global__ void k_fill(const int* __restrict__ idx_hw,
                       const int* __restrict__ idx_agg,
                       const int* __restrict__ off_pix, int* __restrict__ fill_pix,
                       int* __restrict__ list_pix,
                       const int* __restrict__ off_tok, int* __restrict__ fill_tok,
                       int* __restrict__ list_tok) {
    int i = blockIdx.x * blockDim.x + threadIdx.x;
    if (i >= NSAMP) return;
    int b = i >> 14;
    int sp = (b << 14) + idx_hw[i];
    int p = atomicAdd(&fill_pix[sp], 1);
    list_pix[off_pix[sp] + p] = i;
    int st = (b << 12) + idx_agg[i];
    int q = atomicAdd(&fill_tok[st], 1);
    list_tok[off_tok[st] + q] = i;
}

// ---------------------------------------------------------------------------
// K1: build normalized pixel map via gather, bf16 output.
//     8 chains + R19: cross-iteration metadata software pipeline — prefetch
//     (list -> idx_agg) for j+1 while the x-row loads of j are in flight.
__global__ __launch_bounds__(192) void k_xmap(const float* __restrict__ x,
                                              const int* __restrict__ idx_agg,
                                              const int* __restrict__ count_pix,
                                              const int* __restrict__ off_pix,
                                              const int* __restrict__ list_pix,
                                              ushort* __restrict__ xm) {
    int bi0 = blockIdx.x * XPB;              // 8 consecutive pixels, same batch
    int b = bi0 >> 14;
    int c4 = threadIdx.x;                    // 0..191
    const float* xb = x + (size_t)(b * NN) * CC;

    int kk[XPB], st[XPB];
#pragma unroll
    for (int p = 0; p < XPB; ++p) {
        kk[p] = count_pix[bi0 + p];
        st[p] = off_pix[bi0 + p];
    }
    float4 acc[XPB];
#pragma unroll
    for (int p = 0; p < XPB; ++p) acc[p] = make_float4(0.f, 0.f, 0.f, 0.f);

    int kmax = 0;
#pragma unroll
    for (int p = 0; p < XPB; ++p) kmax = max(kmax, kk[p]);

    // prologue: meta for j=0 (index 0 is always safe to read)
    int cur_tok[XPB];
#pragma unroll
    for (int p = 0; p < XPB; ++p) {
        int i = (0 < kk[p]) ? list_pix[st[p]] : 0;
        cur_tok[p] = idx_agg[i];
    }

    for (int j = 0; j < kmax; ++j) {
        // issue next iteration's level-1 meta loads first
        int nxt_i[XPB];
#pragma unroll
        for (int p = 0; p < XPB; ++p)
            nxt_i[p] = (j + 1 < kk[p]) ? list_pix[st[p] + j + 1] : 0;
        // wide row loads for current iteration (addr ready from last iter)
#pragma unroll
        for (int p = 0; p < XPB; ++p) {
            if (j < kk[p]) {
                float4 v = ((const float4*)(xb + (size_t)cur_tok[p] * CC))[c4];
                acc[p].x += v.x; acc[p].y += v.y;
                acc[p].z += v.z; acc[p].w += v.w;
            }
        }
        // level-2 meta for next iteration
#pragma unroll
        for (int p = 0; p < XPB; ++p) cur_tok[p] = idx_agg[nxt_i[p]];
    }
#pragma unroll
    for (int p = 0; p < XPB; ++p) {
        if (kk[p] > 0) {                     // empty rows never read downstream
            float inv = 1.0f / ((float)kk[p] + EPS);
            ushort4 o;
            o.x = f2bf(acc[p].x * inv); o.y = f2bf(acc[p].y * inv);
            o.z = f2bf(acc[p].z * inv); o.w = f2bf(acc[p].w * inv);
            ((ushort4*)(xm + (size_t)(bi0 + p) * CC))[c4] = o;
        }
    }
}

// ---------------------------------------------------------------------------
// K2: depthwise 3x3 conv + bias, LDS-tiled (8x8 pixels x 128 ch per block).
//     bf16 halo tile; count==0 cells zero-filled without global read.
//     f32x2 packed accumulation (v_pk_fma_f32) + 16B staging lanes.
__global__ __launch_bounds__(256, 5) void k_conv(const ushort* __restrict__ xm,
                                                 const int* __restrict__ count_pix,
                                                 const float* __restrict__ w_dw,
                                                 const float* __restrict__ b_dw,
                                                 ushort* __restrict__ ym) {
    __shared__ ushort tile[(TP + 2) * (TP + 2) * TROWU];   // 10*10*136*2 = 27.2 KB
    __shared__ int cnt_halo[(TP + 2) * (TP + 2)];          // 100 ints

    int f = blockIdx.x;
    f = (f & 7) * (CONV_BLOCKS / 8) + (f >> 3);            // bijective XCD swizzle
    int tx = f & 15;
    int ty = (f >> 4) & 15;
    int cblk = (f >> 8) % 6;
    int b = f / 1536;
    int tid = threadIdx.x;

    int c0g = cblk * CSUB;                                 // global channel base
    const ushort* src = xm + (size_t)(b << 14) * CC + c0g;

    // ---- stage halo counts (100 ints; 0 outside image) ----
    if (tid < (TP + 2) * (TP + 2)) {
        int r = tid / 10;
        int c = tid - r * 10;
        int gy = ty * TP + r - 1;
        int gx = tx * TP + c - 1;
        int cnt = 0;
        if (gy >= 0 && gy < HH && gx >= 0 && gx < WW)
            cnt = count_pix[(b << 14) + gy * WW + gx];
        cnt_halo[tid] = cnt;
    }
    __syncthreads();

    // ---- stage 10x10 bf16 halo tile, 16 lanes x 16B per cell ----
    for (int idx = tid; idx < (TP + 2) * (TP + 2) * 16; idx += 256) {
        int lc = idx & 15;                                 // uint4 within cell
        int cell = idx >> 4;                               // 0..99
        int r = cell / 10;
        int c = cell - r * 10;
        uint4 v = make_uint4(0u, 0u, 0u, 0u);
        if (cnt_halo[cell] > 0) {                          // implies in-image
            int gy = ty * TP + r - 1;
            int gx = tx * TP + c - 1;
            v = ((const uint4*)(src + (size_t)(gy * WW + gx) * CC))[lc];
        }
        ((uint4*)(tile + (size_t)cell * TROWU))[lc] = v;
    }
    __syncthreads();

    // ---- per-thread: 4 channels (c4), one pixel column (px), walk 8 rows ----
    int c4 = tid & 31;
    int px = tid >> 5;                                     // 0..7

    // weights as packed pairs: wp01[t]={w[c0][t],w[c1][t]}, wp23 likewise
    f32x2 wp01[9], wp23[9];
    {
        float wreg[36];                                    // [4ch][9taps] contiguous
        const float4* wp = (const float4*)(w_dw + (size_t)(c0g + c4 * 4) * 9);
#pragma unroll
        for (int j = 0; j < 9; ++j) ((float4*)wreg)[j] = wp[j];
#pragma unroll
        for (int t = 0; t < 9; ++t) {
            wp01[t].x = wreg[0 * 9 + t]; wp01[t].y = wreg[1 * 9 + t];
            wp23[t].x = wreg[2 * 9 + t]; wp23[t].y = wreg[3 * 9 + t];
        }
    }
    float4 bias = ((const float4*)(b_dw + c0g))[c4];
    f32x2 bias01; bias01.x = bias.x; bias01.y = bias.y;
    f32x2 bias23; bias23.x = bias.z; bias23.y = bias.w;

    // sliding window as packed pairs; cell read = uint2 (4 bf16)
    f32x2 a01[3][3], a23[3][3];
#pragma unroll
    for (int i = 0; i < 2; ++i)
#pragma unroll
        for (int j = 0; j < 3; ++j) {
            uint2 u = ((const uint2*)(tile + (size_t)(i * (TP + 2) + px + j) * TROWU))[c4];
            a01[i][j] = u32_to_f2(u.x);
            a23[i][j] = u32_to_f2(u.y);
        }

    ushort* dst_base = ym + (size_t)((b << 14) + (ty * TP) * WW + tx * TP + px) * CC
                       + c0g;

#pragma unroll
    for (int oy = 0; oy < TP; ++oy) {
#pragma unroll
        for (int j = 0; j < 3; ++j) {
            uint2 u = ((const uint2*)(tile + (size_t)((oy + 2) * (TP + 2) + px + j) * TROWU))[c4];
            a01[2][j] = u32_to_f2(u.x);
            a23[2][j] = u32_to_f2(u.y);
        }

        if (cnt_halo[(oy + 1) * (TP + 2) + px + 1] > 0) {  // skip dead outputs
            f32x2 acc01 = bias01;
            f32x2 acc23 = bias23;
#pragma unroll
            for (int i = 0; i < 3; ++i) {
#pragma unroll
                for (int j = 0; j < 3; ++j) {
                    int t = i * 3 + j;
                    acc01 += a01[i][j] * wp01[t];          // v_pk_fma_f32
                    acc23 += a23[i][j] * wp23[t];
                }
            }
            ushort4 o;
            o.x = f2bf(acc01.x); o.y = f2bf(acc01.y);
            o.z = f2bf(acc23.x); o.w = f2bf(acc23.y);
            ((ushort4*)(dst_base + (size_t)oy * WW * CC))[c4] = o;
        }

#pragma unroll
        for (int j = 0; j < 3; ++j) {
            a01[0][j] = a01[1][j]; a01[1][j] = a01[2][j];
            a23[0][j] = a23[1][j]; a23[1][j] = a23[2][j];
        }
    }
}

// ---------------------------------------------------------------------------
// K3: per-token gather of conv rows, weighted avg, fused skip.
//     8 chains + R19 metadata software pipeline: prefetch (list -> idx_hw,
//     agg_w) for j+1 while the ym-row loads of j are in flight.
__global__ __launch_bounds__(192) void k_token(const ushort* __restrict__ ym,
                                               const float* __restrict__ x,
                                               const float* __restrict__ agg_w,
                                               const int* __restrict__ idx_hw,
                                               const int* __restrict__ count_tok,
                                               const int* __restrict__ off_tok,
                                               const int* __restrict__ list_tok,
                                               const float* __restrict__ w_skip,
                                               float* __restrict__ out) {
    int bi0 = blockIdx.x * TPB;              // 8 consecutive tokens, same batch
    int b = bi0 >> 12;                       // NN = 4096
    int c4 = threadIdx.x;
    const ushort* yb = ym + (size_t)(b << 14) * CC;

    int kk[TPB], st[TPB];
#pragma unroll
    for (int p = 0; p < TPB; ++p) {
        kk[p] = count_tok[bi0 + p];
        st[p] = off_tok[bi0 + p];
    }
    float4 acc[TPB];
    float tw[TPB];
#pragma unroll
    for (int p = 0; p < TPB; ++p) {
        acc[p] = make_float4(0.f, 0.f, 0.f, 0.f);
        tw[p] = 0.f;
    }

    int kmax = 0;
#pragma unroll
    for (int p = 0; p < TPB; ++p) kmax = max(kmax, kk[p]);

    // prologue: meta for j=0 (index 0 always safe)
    float cur_w[TPB];
    int cur_pix[TPB];
#pragma unroll
    for (int p = 0; p < TPB; ++p) {
        int i = (0 < kk[p]) ? list_tok[st[p]] : 0;
        cur_w[p] = agg_w[i];
        cur_pix[p] = idx_hw[i];
    }

    for (int j = 0; j < kmax; ++j) {
        // issue next iteration's level-1 meta loads first
        int nxt_i[TPB];
#pragma unroll
        for (int p = 0; p < TPB; ++p)
            nxt_i[p] = (j + 1 < kk[p]) ? list_tok[st[p] + j + 1] : 0;
        // wide row loads for current iteration (addr ready from last iter)
#pragma unroll
        for (int p = 0; p < TPB; ++p) {
            if (j < kk[p]) {
                float w = cur_w[p];
                float4 v = us4_to_f4(((const ushort4*)(yb + (size_t)cur_pix[p] * CC))[c4]);
                acc[p].x += w * v.x; acc[p].y += w * v.y;
                acc[p].z += w * v.z; acc[p].w += w * v.w;
                tw[p] += w;
            }
        }
        // level-2 meta for next iteration
#pragma unroll
        for (int p = 0; p < TPB; ++p) {
            cur_w[p] = agg_w[nxt_i[p]];
            cur_pix[p] = idx_hw[nxt_i[p]];
        }
    }

    float4 ws = ((const float4*)w_skip)[c4];
#pragma unroll
    for (int p = 0; p < TPB; ++p) {
        float inv = 1.0f / (tw[p] + EPS);
        float4 xv = ((const float4*)(x + (size_t)(bi0 + p) * CC))[c4];
        float4 o;
        o.x = acc[p].x * inv + xv.x * ws.x;
        o.y = acc[p].y * inv + xv.y * ws.y;
        o.z = acc[p].z * inv + xv.z * ws.z;
        o.w = acc[p].w * inv + xv.w * ws.w;
        ((float4*)(out + (size_t)(bi0 + p) * CC))[c4] = o;
    }
}

// ---------------------------------------------------------------------------
extern "C" void kernel_launch(void* const* d_in, const int* in_sizes, int n_in,
                              void* d_out, int out_size, void* d_ws, size_t ws_size,
                              hipStream_t stream) {
    const float* x       = (const float*)d_in[0];   // [B,N,C]
    const float* loc     = (const float*)d_in[1];   // [B,N0,2]
    const int*   idx_agg = (const int*)d_in[2];     // [B,N0]
    const float* agg_w   = (const float*)d_in[3];   // [B,N0]
    const float* w_dw    = (const float*)d_in[6];   // [C,1,3,3]
    const float* b_dw    = (const float*)d_in[7];   // [C]
    const float* w_skip  = (const float*)d_in[8];   // [C]
    float* out = (float*)d_out;
    char* ws = (char*)d_ws;

    size_t off = 0;
    // zeroed region (one small memset): counts + fill cursors
    int* count_pix = (int*)(ws + off); off += (size_t)NPIX * 4;
    int* fill_pix  = (int*)(ws + off); off += (size_t)NPIX * 4;
    int* count_tok = (int*)(ws + off); off += (size_t)NTOK * 4;
    int* fill_tok  = (int*)(ws + off); off += (size_t)NTOK * 4;
    size_t zero_bytes = off;
    // fully-written regions
    int* idx_hw   = (int*)(ws + off); off += (size_t)NSAMP * 4;
    int* off_pix  = (int*)(ws + off); off += (size_t)NPIX * 4;
    int* list_pix = (int*)(ws + off); off += (size_t)NSAMP * 4;
    int* off_tok  = (int*)(ws + off); off += (size_t)NTOK * 4;
    int* list_tok = (int*)(ws + off); off += (size_t)NSAMP * 4;
    ushort* xm = (ushort*)(ws + off); off += (size_t)NPIX * CC * 2;   // 100.7 MB bf16
    ushort* ym = (ushort*)(ws + off); off += (size_t)NPIX * CC * 2;   // 100.7 MB bf16
    // total ~202.7 MB — within the proven-safe workspace budget (R0 used 252 MB)

    hipMemsetAsync(ws, 0, zero_bytes, stream);

    hipLaunchKernelGGL(k_idx, dim3(NSAMP / 256), dim3(256), 0, stream,
                       loc, idx_agg, idx_hw, count_pix, count_tok);
    hipLaunchKernelGGL(k_scan, dim3(8), dim3(1024), 0, stream,
                       count_pix, off_pix, count_tok, off_tok);
    hipLaunchKernelGGL(k_fill, dim3(NSAMP / 256), dim3(256), 0, stream,
                       idx_hw, idx_agg, off_pix, fill_pix, list_pix,
                       off_tok, fill_tok, list_tok);
    hipLaunchKernelGGL(k_xmap, dim3(NPIX / XPB), dim3(192), 0, stream,
                       x, idx_agg, count_pix, off_pix, list_pix, xm);
    hipLaunchKernelGGL(k_conv, dim3(CONV_BLOCKS), dim3(256), 0, stream,
                       xm, count_pix, w_dw, b_dw, ym);
    hipLaunchKernelGGL(k_token, dim3(NTOK / TPB), dim3(192), 0, stream,
                       ym, x, agg_w, idx_hw, count_tok, off_tok, list_tok,
                       w_skip, out);
}